// Round 5
// baseline (1572.357 us; speedup 1.0000x reference)
//
#include <hip/hip_runtime.h>
#include <stdint.h>

#define F 16
#define CDIM 320
#define DDIM 4096
#define NSEQ 8192
#define WPB 4
#define THREADS 256
#define NT 20
#define KS 10

typedef __attribute__((ext_vector_type(8))) short short8;
typedef __attribute__((ext_vector_type(4))) float f32x4;

__device__ __forceinline__ unsigned short f2bf(float f) {
    union { float f; uint32_t u; } v; v.f = f;
    uint32_t r = v.u + 0x7FFFu + ((v.u >> 16) & 1u);   // RTNE
    return (unsigned short)(r >> 16);
}
__device__ __forceinline__ float bf2f(unsigned short h) {
    union { uint32_t u; float f; } v; v.u = ((uint32_t)h) << 16;
    return v.f;
}
// full-row swizzle: [16][320] bf16 tile, stride 640 B (16B chunks, xor low3 of row)
__device__ __forceinline__ int swz(int row, int b) {
    return row * 640 + (b ^ ((row & 7) << 4));
}
// half-row swizzle: [16][160] bf16 tile, stride 320 B (20 chunks/row, xor low2 only
// so the swizzled chunk index stays < 20)
__device__ __forceinline__ int hswz(int row, int b) {
    return row * 320 + (b ^ ((row & 3) << 4));
}

// One-time: pack Wq/Wk/Wv/Wo (fp32 row-major [320][320]) into bf16 B-fragment
// order. Fragment (m, nt, ks) is a 1KB block: lane (g,lr) holds
// W[nt*16+lr][ks*32+g*8 .. +7]. Byte offset = ((m*NT+nt)*KS+ks)*1024 + lane*16.
__global__ __launch_bounds__(256)
void pack_weights_kernel(const float* __restrict__ Wq, const float* __restrict__ Wk,
                         const float* __restrict__ Wv, const float* __restrict__ Wo,
                         char* __restrict__ pk)
{
    const int t = blockIdx.x * 256 + threadIdx.x;
    if (t >= 4 * NT * KS * 64) return;
    const int lane = t & 63;
    const int rest = t >> 6;
    const int ks = rest % KS;
    const int nt = (rest / KS) % NT;
    const int m  = rest / (KS * NT);
    const float* W = (m == 0) ? Wq : (m == 1) ? Wk : (m == 2) ? Wv : Wo;
    const int g = lane >> 4, lr = lane & 15;
    const float* src = W + (size_t)(nt * 16 + lr) * CDIM + ks * 32 + g * 8;
    const f32x4 a = *(const f32x4*)src;
    const f32x4 b = *(const f32x4*)(src + 4);
    float vals[8] = {a[0], a[1], a[2], a[3], b[0], b[1], b[2], b[3]};
    short8 o;
#pragma unroll
    for (int j = 0; j < 8; ++j) o[j] = (short)f2bf(vals[j]);
    *(short8*)(pk + (size_t)t * 16) = o;
}

// launch_bounds min-waves=2: cap 256 VGPR. Bounds of 3/4 (R3/R4) made the
// allocator spill inside unrolled loops -> ~3 GB scratch traffic. Occupancy
// comes from LDS instead: 40 KB/block -> 4 blocks/CU; actual VGPR use ~100
// -> 4 waves/SIMD anyway.
__global__ __launch_bounds__(THREADS, 2)
void temporal_attn_kernel(const float* __restrict__ hs,
                          const char* __restrict__ wpk,
                          const float* __restrict__ bo,
                          float* __restrict__ out)
{
    extern __shared__ __align__(16) char smem[];
    // per-wave 10240 B: bufA [16][160] bf16 (K half) + bufB [16][160] bf16
    // (Q, then V half). After both passes the 10240 B is reused as the
    // attention-out [16][320] overlay. No __syncthreads anywhere.
    const int tid  = threadIdx.x;
    const int lane = tid & 63;
    const int wave = tid >> 6;
    const int g    = lane >> 4;
    const int lr   = lane & 15;

    const int seq = blockIdx.x * WPB + wave;
    const int bi  = seq >> 12;
    const int di  = seq & (DDIM - 1);

    char* const bufA = smem + wave * 10240;
    char* const bufB = bufA + 5120;
    char* const aob  = bufA;              // overlay, used after both passes
    const char* const wl = wpk + lane * 16;

    // ---- load x rows, add PE, convert to bf16 A-fragments (40 VGPR) ----
    const float* xrow = hs + ((size_t)(bi * F + lr) * DDIM + di) * CDIM;
    short8 axk[KS];
#pragma unroll
    for (int ks = 0; ks < KS; ++ks) {
        const int k0 = ks * 32 + g * 8;
        const f32x4 a = *(const f32x4*)(xrow + k0);
        const f32x4 b = *(const f32x4*)(xrow + k0 + 4);
        float xv[8] = {a[0], a[1], a[2], a[3], b[0], b[1], b[2], b[3]};
#pragma unroll
        for (int jj = 0; jj < 4; ++jj) {
            const float c0 = (float)(k0 + 2 * jj);
            const float dv = __expf(c0 * -0.028782313662425575f); // -ln(1e4)/320
            const float ang = (float)lr * dv;                      // pos = frame
            xv[2 * jj]     += __sinf(ang);
            xv[2 * jj + 1] += __cosf(ang);
        }
        short8 t;
#pragma unroll
        for (int j = 0; j < 8; ++j) t[j] = (short)f2bf(xv[j]);
        axk[ks] = t;
    }

    // half projection: matrix m, head-half h2 (cols 160*h2 .. +159) -> dst
    auto projh = [&](int m, int h2, char* dst) {
#pragma unroll 2
        for (int ntp = 0; ntp < 10; ++ntp) {
            f32x4 acc = {0.f, 0.f, 0.f, 0.f};
#pragma unroll
            for (int ks = 0; ks < KS; ++ks) {
                short8 b = *(const short8*)(wl +
                    (size_t)((m * NT + h2 * 10 + ntp) * KS + ks) * 1024);
                acc = __builtin_amdgcn_mfma_f32_16x16x32_bf16(axk[ks], b, acc, 0, 0, 0);
            }
#pragma unroll
            for (int r = 0; r < 4; ++r)
                *(short*)(dst + hswz(g * 4 + r, (ntp * 16 + lr) * 2)) = (short)f2bf(acc[r]);
        }
    };

    const float scale = 0.15811388300841897f;  // 40^-0.5
    short8 aopk[2][5];

#pragma unroll      // h2 must be compile-time so aopk indexing stays static
    for (int h2 = 0; h2 < 2; ++h2) {
        projh(0, h2, bufB);    // Q half -> bufB
        projh(1, h2, bufA);    // K half -> bufA

        // scores, chunked over d (8 at a time); q read straight from LDS
        float s[F];
#pragma unroll
        for (int kk = 0; kk < F; ++kk) s[kk] = 0.f;
#pragma unroll
        for (int j5 = 0; j5 < 5; ++j5) {
            short8 q8 = *(const short8*)(bufB + hswz(lr, g * 80 + j5 * 16));
            float qf[8];
#pragma unroll
            for (int j = 0; j < 8; ++j) qf[j] = bf2f((unsigned short)q8[j]);
#pragma unroll
            for (int kk = 0; kk < F; ++kk) {
                short8 k8 = *(const short8*)(bufA + hswz(kk, g * 80 + j5 * 16));
#pragma unroll
                for (int j = 0; j < 8; ++j) s[kk] += qf[j] * bf2f((unsigned short)k8[j]);
            }
        }
        // causal mask + softmax, in place (s becomes normalized p)
        float m = -1e30f;
#pragma unroll
        for (int kk = 0; kk < F; ++kk) {
            s[kk] = (kk <= lr) ? s[kk] * scale : -1e30f;
            m = fmaxf(m, s[kk]);
        }
        float sum = 0.f;
#pragma unroll
        for (int kk = 0; kk < F; ++kk) { s[kk] = __expf(s[kk] - m); sum += s[kk]; }
        const float inv = 1.f / sum;
#pragma unroll
        for (int kk = 0; kk < F; ++kk) s[kk] *= inv;

        projh(2, h2, bufB);    // V half overwrites Q (q dead after scores)

        // PV, one 8-wide d-chunk at a time, packed straight to bf16 regs
#pragma unroll
        for (int j5 = 0; j5 < 5; ++j5) {
            float a8[8];
#pragma unroll
            for (int j = 0; j < 8; ++j) a8[j] = 0.f;
#pragma unroll
            for (int kk = 0; kk < F; ++kk) {
                short8 v8 = *(const short8*)(bufB + hswz(kk, g * 80 + j5 * 16));
#pragma unroll
                for (int j = 0; j < 8; ++j) a8[j] += s[kk] * bf2f((unsigned short)v8[j]);
            }
            short8 t;
#pragma unroll
            for (int j = 0; j < 8; ++j) t[j] = (short)f2bf(a8[j]);
            aopk[h2][j5] = t;
        }
    }

    // write attention-out into the full [16][320] overlay buffer
#pragma unroll
    for (int h2 = 0; h2 < 2; ++h2)
#pragma unroll
        for (int j5 = 0; j5 < 5; ++j5)
            *(short8*)(aob + swz(lr, (g + 4 * h2) * 80 + j5 * 16)) = aopk[h2][j5];

    // ---- output projection: out = ao @ Wo.T + bo ----
    short8 aof[KS];
#pragma unroll
    for (int ks = 0; ks < KS; ++ks)
        aof[ks] = *(const short8*)(aob + swz(lr, ks * 64 + g * 16));

#pragma unroll 1
    for (int np = 0; np < 10; ++np) {
        f32x4 a0 = {0.f, 0.f, 0.f, 0.f};
        f32x4 a1 = {0.f, 0.f, 0.f, 0.f};
#pragma unroll
        for (int ks = 0; ks < KS; ++ks) {
            short8 b = *(const short8*)(wl + (size_t)((3 * NT + 2 * np) * KS + ks) * 1024);
            a0 = __builtin_amdgcn_mfma_f32_16x16x32_bf16(aof[ks], b, a0, 0, 0, 0);
        }
#pragma unroll
        for (int ks = 0; ks < KS; ++ks) {
            short8 b = *(const short8*)(wl + (size_t)((3 * NT + 2 * np + 1) * KS + ks) * 1024);
            a1 = __builtin_amdgcn_mfma_f32_16x16x32_bf16(aof[ks], b, a1, 0, 0, 0);
        }
        const int c0 = 2 * np * 16 + lr;
        const int c1 = c0 + 16;
        const float bias0 = bo[c0];
        const float bias1 = bo[c1];
        // paired stores: cols c0 (16 lanes, 64 B) + c1 (next 64 B) issued
        // back-to-back cover one full 128 B line per output row
#pragma unroll
        for (int r = 0; r < 4; ++r) {
            float* rowp = out + ((size_t)(bi * F + g * 4 + r) * DDIM + di) * CDIM;
            rowp[c0] = a0[r] + bias0;
            rowp[c1] = a1[r] + bias1;
        }
    }
}

extern "C" void kernel_launch(void* const* d_in, const int* in_sizes, int n_in,
                              void* d_out, int out_size, void* d_ws, size_t ws_size,
                              hipStream_t stream) {
    const float* hs = (const float*)d_in[0];
    const float* Wq = (const float*)d_in[1];
    const float* Wk = (const float*)d_in[2];
    const float* Wv = (const float*)d_in[3];
    const float* Wo = (const float*)d_in[4];
    const float* bo = (const float*)d_in[5];
    float* out = (float*)d_out;
    char* wpk = (char*)d_ws;   // 4*200*1024 = 819200 B of packed bf16 weights

    pack_weights_kernel<<<dim3((4 * NT * KS * 64 + 255) / 256), dim3(256), 0, stream>>>(
        Wq, Wk, Wv, Wo, wpk);

    const int lds = WPB * 10240;   // 40960 B -> up to 4 blocks/CU by LDS
    (void)hipFuncSetAttribute((const void*)temporal_attn_kernel,
                              hipFuncAttributeMaxDynamicSharedMemorySize, lds);
    temporal_attn_kernel<<<dim3(NSEQ / WPB), dim3(THREADS), lds, stream>>>(
        hs, wpk, bo, out);
}

// Round 6
// 275.389 us; speedup vs baseline: 5.7096x; 5.7096x over previous
//
#include <hip/hip_runtime.h>
#include <stdint.h>

#define F 16
#define CDIM 320
#define DDIM 4096
#define NSEQ 8192
#define WPB 4
#define THREADS 256
#define NT 20
#define KS 10

typedef __attribute__((ext_vector_type(8))) short short8;
typedef __attribute__((ext_vector_type(4))) float f32x4;

__device__ __forceinline__ unsigned short f2bf(float f) {
    union { float f; uint32_t u; } v; v.f = f;
    uint32_t r = v.u + 0x7FFFu + ((v.u >> 16) & 1u);   // RTNE
    return (unsigned short)(r >> 16);
}
__device__ __forceinline__ float bf2f(unsigned short h) {
    union { uint32_t u; float f; } v; v.u = ((uint32_t)h) << 16;
    return v.f;
}
// XOR swizzle inside a [16][320] bf16 row-major tile (row stride 640 B).
// 16B chunks; chunk ^ (row&7) is a bijection per row -> disjoint regions
// stay disjoint under the swizzle.
__device__ __forceinline__ int swz(int row, int b) {
    return row * 640 + (b ^ ((row & 7) << 4));
}

// One-time: pack Wq/Wk/Wv/Wo (fp32 row-major [320][320]) into bf16 B-fragment
// order. Fragment (m, nt, ks) is a 1KB block: lane (g,lr) holds
// W[nt*16+lr][ks*32+g*8 .. +7]. Byte offset = ((m*NT+nt)*KS+ks)*1024 + lane*16.
__global__ __launch_bounds__(256)
void pack_weights_kernel(const float* __restrict__ Wq, const float* __restrict__ Wk,
                         const float* __restrict__ Wv, const float* __restrict__ Wo,
                         char* __restrict__ pk)
{
    const int t = blockIdx.x * 256 + threadIdx.x;
    if (t >= 4 * NT * KS * 64) return;
    const int lane = t & 63;
    const int rest = t >> 6;
    const int ks = rest % KS;
    const int nt = (rest / KS) % NT;
    const int m  = rest / (KS * NT);
    const float* W = (m == 0) ? Wq : (m == 1) ? Wk : (m == 2) ? Wv : Wo;
    const int g = lane >> 4, lr = lane & 15;
    const float* src = W + (size_t)(nt * 16 + lr) * CDIM + ks * 32 + g * 8;
    const f32x4 a = *(const f32x4*)src;
    const f32x4 b = *(const f32x4*)(src + 4);
    float vals[8] = {a[0], a[1], a[2], a[3], b[0], b[1], b[2], b[3]};
    short8 o;
#pragma unroll
    for (int j = 0; j < 8; ++j) o[j] = (short)f2bf(vals[j]);
    *(short8*)(pk + (size_t)t * 16) = o;
}

// R2 structure (proven 433us clean): full-width passes, 20KB/wave LDS,
// bounds (256,2). R3-R5 lesson: do NOT unroll global-load-bearing passes
// into one giant region, do NOT tighten launch bounds.
__global__ __launch_bounds__(THREADS, 2)
void temporal_attn_kernel(const float* __restrict__ hs,
                          const char* __restrict__ wpk,
                          const float* __restrict__ bo,
                          float* __restrict__ out)
{
    extern __shared__ __align__(16) char smem[];
    const int tid  = threadIdx.x;
    const int lane = tid & 63;
    const int wave = tid >> 6;
    const int g    = lane >> 4;
    const int lr   = lane & 15;

    const int seq = blockIdx.x * WPB + wave;
    const int bi  = seq >> 12;
    const int di  = seq & (DDIM - 1);

    char* const kbuf = smem + wave * 20480;   // Q, then K, then attn-out
    char* const vbuf = kbuf + 10240;          // V
    const char* const wl = wpk + lane * 16;

    // ---- load x rows, add PE, convert to bf16 A-fragments ----
    const float* xrow = hs + ((size_t)(bi * F + lr) * DDIM + di) * CDIM;
    short8 axk[KS];
#pragma unroll
    for (int ks = 0; ks < KS; ++ks) {
        const int k0 = ks * 32 + g * 8;
        const f32x4 a = __builtin_nontemporal_load((const f32x4*)(xrow + k0));
        const f32x4 b = __builtin_nontemporal_load((const f32x4*)(xrow + k0 + 4));
        float xv[8] = {a[0], a[1], a[2], a[3], b[0], b[1], b[2], b[3]};
#pragma unroll
        for (int jj = 0; jj < 4; ++jj) {
            const float c0 = (float)(k0 + 2 * jj);
            const float dv = __expf(c0 * -0.028782313662425575f); // -ln(1e4)/320
            const float ang = (float)lr * dv;                      // pos = frame
            xv[2 * jj]     += __sinf(ang);
            xv[2 * jj + 1] += __cosf(ang);
        }
        short8 t;
#pragma unroll
        for (int j = 0; j < 8; ++j) t[j] = (short)f2bf(xv[j]);
        axk[ks] = t;
    }

    // ---- projection pass, ping-pong pipelined over 20 n-tiles ----
    // loads for tile n+1 issue before the MFMAs of tile n, so each 10-load
    // L2 batch is covered by ~10 MFMAs + C-write of the previous tile.
    auto proj = [&](int m, char* dst) {
        const char* base = wl + (size_t)(m * NT) * KS * 1024;
        short8 fa[KS], fb[KS];
#pragma unroll
        for (int ks = 0; ks < KS; ++ks)
            fa[ks] = *(const short8*)(base + (size_t)ks * 1024);
#pragma unroll 1
        for (int np = 0; np < 10; ++np) {
#pragma unroll
            for (int ks = 0; ks < KS; ++ks)
                fb[ks] = *(const short8*)(base + (size_t)((2 * np + 1) * KS + ks) * 1024);
            f32x4 a0 = {0.f, 0.f, 0.f, 0.f};
#pragma unroll
            for (int ks = 0; ks < KS; ++ks)
                a0 = __builtin_amdgcn_mfma_f32_16x16x32_bf16(axk[ks], fa[ks], a0, 0, 0, 0);
            if (np < 9) {
#pragma unroll
                for (int ks = 0; ks < KS; ++ks)
                    fa[ks] = *(const short8*)(base + (size_t)((2 * np + 2) * KS + ks) * 1024);
            }
            f32x4 a1 = {0.f, 0.f, 0.f, 0.f};
#pragma unroll
            for (int ks = 0; ks < KS; ++ks)
                a1 = __builtin_amdgcn_mfma_f32_16x16x32_bf16(axk[ks], fb[ks], a1, 0, 0, 0);
#pragma unroll
            for (int r = 0; r < 4; ++r) {
                const int row = g * 4 + r;
                *(short*)(dst + swz(row, (2 * np * 16 + lr) * 2))       = (short)f2bf(a0[r]);
                *(short*)(dst + swz(row, ((2 * np + 1) * 16 + lr) * 2)) = (short)f2bf(a1[r]);
            }
        }
    };

    proj(0, kbuf);                       // Q -> kbuf (transient)
    short8 qreg[2][5];                   // statically indexed everywhere
#pragma unroll
    for (int h2 = 0; h2 < 2; ++h2)
#pragma unroll
        for (int j5 = 0; j5 < 5; ++j5)
            qreg[h2][j5] = *(const short8*)(kbuf + swz(lr, (g + 4 * h2) * 80 + j5 * 16));
    proj(1, kbuf);                       // K overwrites Q
    proj(2, vbuf);                       // V

    // ---- causal attention; lane = (q-row = lr, head = g + 4*h2) ----
    // h2 fully unrolled (attention only, no global loads -> small region).
    // h2=0 writes attn-out into kbuf chunks {0..19}^r; h2=1 reads K chunks
    // {20..39}^r -- disjoint since chunk^r is a bijection.
    const float scale = 0.15811388300841897f;  // 40^-0.5
#pragma unroll
    for (int h2 = 0; h2 < 2; ++h2) {
        const int cb = (g + 4 * h2) * 80;
        float s[F];
#pragma unroll
        for (int kk = 0; kk < F; ++kk) s[kk] = 0.f;
#pragma unroll
        for (int j5 = 0; j5 < 5; ++j5) {
            float qf[8];
#pragma unroll
            for (int j = 0; j < 8; ++j) qf[j] = bf2f((unsigned short)qreg[h2][j5][j]);
#pragma unroll
            for (int kk = 0; kk < F; ++kk) {
                short8 k8 = *(const short8*)(kbuf + swz(kk, cb + j5 * 16));
#pragma unroll
                for (int j = 0; j < 8; ++j) s[kk] += qf[j] * bf2f((unsigned short)k8[j]);
            }
        }
        float m = -1e30f;
#pragma unroll
        for (int kk = 0; kk < F; ++kk) {
            s[kk] = (kk <= lr) ? s[kk] * scale : -1e30f;
            m = fmaxf(m, s[kk]);
        }
        float sum = 0.f;
#pragma unroll
        for (int kk = 0; kk < F; ++kk) { s[kk] = __expf(s[kk] - m); sum += s[kk]; }
        const float inv = 1.f / sum;
#pragma unroll
        for (int kk = 0; kk < F; ++kk) s[kk] *= inv;

        // PV chunked: one 8-wide d-chunk at a time, packed straight to LDS
#pragma unroll
        for (int j5 = 0; j5 < 5; ++j5) {
            float a8[8];
#pragma unroll
            for (int j = 0; j < 8; ++j) a8[j] = 0.f;
#pragma unroll
            for (int kk = 0; kk < F; ++kk) {
                short8 v8 = *(const short8*)(vbuf + swz(kk, cb + j5 * 16));
#pragma unroll
                for (int j = 0; j < 8; ++j) a8[j] += s[kk] * bf2f((unsigned short)v8[j]);
            }
            short8 t;
#pragma unroll
            for (int j = 0; j < 8; ++j) t[j] = (short)f2bf(a8[j]);
            *(short8*)(kbuf + swz(lr, cb + j5 * 16)) = t;
        }
    }

    // ---- output projection: out = ao @ Wo.T + bo, pipelined + paired stores ----
    short8 aof[KS];
#pragma unroll
    for (int ks = 0; ks < KS; ++ks)
        aof[ks] = *(const short8*)(kbuf + swz(lr, ks * 64 + g * 16));

    {
        const char* base = wl + (size_t)(3 * NT) * KS * 1024;
        short8 fa[KS], fb[KS];
#pragma unroll
        for (int ks = 0; ks < KS; ++ks)
            fa[ks] = *(const short8*)(base + (size_t)ks * 1024);
#pragma unroll 1
        for (int np = 0; np < 10; ++np) {
#pragma unroll
            for (int ks = 0; ks < KS; ++ks)
                fb[ks] = *(const short8*)(base + (size_t)((2 * np + 1) * KS + ks) * 1024);
            f32x4 a0 = {0.f, 0.f, 0.f, 0.f};
#pragma unroll
            for (int ks = 0; ks < KS; ++ks)
                a0 = __builtin_amdgcn_mfma_f32_16x16x32_bf16(aof[ks], fa[ks], a0, 0, 0, 0);
            if (np < 9) {
#pragma unroll
                for (int ks = 0; ks < KS; ++ks)
                    fa[ks] = *(const short8*)(base + (size_t)((2 * np + 2) * KS + ks) * 1024);
            }
            f32x4 a1 = {0.f, 0.f, 0.f, 0.f};
#pragma unroll
            for (int ks = 0; ks < KS; ++ks)
                a1 = __builtin_amdgcn_mfma_f32_16x16x32_bf16(aof[ks], fb[ks], a1, 0, 0, 0);

            const int c0 = 2 * np * 16 + lr;
            const int c1 = c0 + 16;
            const float bias0 = bo[c0];
            const float bias1 = bo[c1];
            // rows are 1280B-aligned; pair np covers bytes [np*128, +128):
            // exactly one full 128B line per output row, no write amp.
#pragma unroll
            for (int r = 0; r < 4; ++r) {
                float* rowp = out + ((size_t)(bi * F + g * 4 + r) * DDIM + di) * CDIM;
                rowp[c0] = a0[r] + bias0;
                rowp[c1] = a1[r] + bias1;
            }
        }
    }
}

extern "C" void kernel_launch(void* const* d_in, const int* in_sizes, int n_in,
                              void* d_out, int out_size, void* d_ws, size_t ws_size,
                              hipStream_t stream) {
    const float* hs = (const float*)d_in[0];
    const float* Wq = (const float*)d_in[1];
    const float* Wk = (const float*)d_in[2];
    const float* Wv = (const float*)d_in[3];
    const float* Wo = (const float*)d_in[4];
    const float* bo = (const float*)d_in[5];
    float* out = (float*)d_out;
    char* wpk = (char*)d_ws;   // 4*200*1024 = 819200 B of packed bf16 weights

    pack_weights_kernel<<<dim3((4 * NT * KS * 64 + 255) / 256), dim3(256), 0, stream>>>(
        Wq, Wk, Wv, Wo, wpk);

    const int lds = WPB * 20480;   // 81920 B -> 2 blocks/CU (8 waves/CU)
    (void)hipFuncSetAttribute((const void*)temporal_attn_kernel,
                              hipFuncAttributeMaxDynamicSharedMemorySize, lds);
    temporal_attn_kernel<<<dim3(NSEQ / WPB), dim3(THREADS), lds, stream>>>(
        hs, wpk, bo, out);
}